// Round 5
// baseline (699.571 us; speedup 1.0000x reference)
//
#include <hip/hip_runtime.h>
#include <cstdint>
#include <cstddef>

// Problem constants
#define BB 8
#define SS 2048
#define DD 512

typedef __attribute__((ext_vector_type(8))) short bf16x8;
typedef __attribute__((ext_vector_type(4))) float f32x4;
typedef __attribute__((ext_vector_type(4))) unsigned int u32x4;

__device__ __forceinline__ unsigned short f2bf(float f) {
  unsigned int u = __builtin_bit_cast(unsigned int, f);
  u = (u + 0x7FFFu + ((u >> 16) & 1u)) >> 16;  // RNE
  return (unsigned short)u;
}
__device__ __forceinline__ float bf2f(unsigned short s) {
  return __builtin_bit_cast(float, ((unsigned int)s) << 16);
}

__device__ __forceinline__ void gload_lds16(const unsigned short* g, unsigned short* l) {
  __builtin_amdgcn_global_load_lds(
      (const __attribute__((address_space(1))) void*)g,
      (__attribute__((address_space(3))) void*)l, 16, 0, 0);
}

// ---------------------------------------------------------------------------
// 128x128-tile bf16 GEMM mainloop (m97 structure) — used by qkv projection.
// ---------------------------------------------------------------------------
__device__ __forceinline__ void gemm_tile(
    const unsigned short* __restrict__ A,
    const unsigned short* __restrict__ B,
    int K, unsigned short* lA, unsigned short* lB,
    f32x4 acc[4][4], size_t m0, size_t n0)
{
  const int t = threadIdx.x;
  const int l = t & 63;
  const int w = t >> 6;
  const int wr = w >> 1, wc = w & 1;
  const size_t K64 = (size_t)K * 64;

  const unsigned short* gA = A + (m0 + (size_t)(t >> 2)) * (size_t)K + (size_t)((t & 3) * 8);
  const unsigned short* gB = B + (n0 + (size_t)(t >> 2)) * (size_t)K + (size_t)((t & 3) * 8);

  const int ar = (wr * 64 + (l & 15)) * 32 + (l >> 4) * 8;
  const int br = (wc * 64 + (l & 15)) * 32 + (l >> 4) * 8;

  const int nk = K >> 5;
  int buf = 0;

  gload_lds16(gA, lA + t * 8);
  gload_lds16(gA + K64, lA + 2048 + t * 8);
  gload_lds16(gB, lB + t * 8);
  gload_lds16(gB + K64, lB + 2048 + t * 8);

  for (int kt = 0; kt < nk; ++kt) {
    __syncthreads();
    if (kt + 1 < nk) {
      const int ko = (kt + 1) << 5;
      const int lo = (buf ^ 1) * 4096;
      gload_lds16(gA + ko, lA + lo + t * 8);
      gload_lds16(gA + ko + K64, lA + lo + 2048 + t * 8);
      gload_lds16(gB + ko, lB + lo + t * 8);
      gload_lds16(gB + ko + K64, lB + lo + 2048 + t * 8);
    }
    const unsigned short* pa = lA + buf * 4096 + ar;
    const unsigned short* pb = lB + buf * 4096 + br;
    bf16x8 af[4], bfr[4];
#pragma unroll
    for (int m = 0; m < 4; ++m) af[m] = *(const bf16x8*)(pa + m * 512);
#pragma unroll
    for (int n = 0; n < 4; ++n) bfr[n] = *(const bf16x8*)(pb + n * 512);
#pragma unroll
    for (int m = 0; m < 4; ++m)
#pragma unroll
      for (int n = 0; n < 4; ++n)
        acc[m][n] = __builtin_amdgcn_mfma_f32_16x16x32_bf16(af[m], bfr[n], acc[m][n], 0, 0, 0);
    buf ^= 1;
  }
}

// ---------------------------------------------------------------------------
// Kernel 1: convert X and Wq|Wk|Wv fp32 -> bf16 into ws.
// ---------------------------------------------------------------------------
__global__ __launch_bounds__(256) void convert_k(
    const float* __restrict__ X, const float* __restrict__ Wq,
    const float* __restrict__ Wk, const float* __restrict__ Wv,
    unsigned short* __restrict__ dst)
{
  const size_t NXe = (size_t)BB * SS * DD;  // 8388608
  const size_t NWe = (size_t)DD * DD;       // 262144
  size_t i = ((size_t)blockIdx.x * 256 + threadIdx.x) * 4;
  const float* src;
  size_t off;
  if (i < NXe)                { src = X;  off = i; }
  else if (i < NXe + NWe)     { src = Wq; off = i - NXe; }
  else if (i < NXe + 2 * NWe) { src = Wk; off = i - NXe - NWe; }
  else                        { src = Wv; off = i - NXe - 2 * NWe; }
  float4 f = *(const float4*)(src + off);
  ushort4 o;
  o.x = f2bf(f.x); o.y = f2bf(f.y); o.z = f2bf(f.z); o.w = f2bf(f.w);
  *(ushort4*)(dst + i) = o;
}

// ---------------------------------------------------------------------------
// Kernel 2: QKV projections. z=0 -> Q [16384,512], z=1 -> K [16384,512],
// z=2 -> V transposed per batch: Vt[b][d][s].
// ---------------------------------------------------------------------------
__global__ __launch_bounds__(256, 2) void qkv_gemm_k(
    const unsigned short* __restrict__ Xb,
    const unsigned short* __restrict__ Wall,
    unsigned short* __restrict__ Qb,
    unsigned short* __restrict__ Kb,
    unsigned short* __restrict__ Vtb)
{
  __shared__ __align__(16) unsigned short lA[8192];
  __shared__ __align__(16) unsigned short lB[8192];
  const int z = blockIdx.z;
  const unsigned short* Bw = Wall + (size_t)z * (DD * DD);
  const size_t m0 = (size_t)blockIdx.y * 128;
  const size_t n0 = (size_t)blockIdx.x * 128;
  f32x4 acc[4][4];
#pragma unroll
  for (int m = 0; m < 4; ++m)
#pragma unroll
    for (int n = 0; n < 4; ++n) acc[m][n] = (f32x4){0.f, 0.f, 0.f, 0.f};

  gemm_tile(Xb, Bw, DD, lA, lB, acc, m0, n0);

  const int t = threadIdx.x, l = t & 63, w = t >> 6, wr = w >> 1, wc = w & 1;
  const size_t rb = m0 + (size_t)(wr * 64 + ((l >> 4) * 4));
  const int cb = (int)n0 + wc * 64 + (l & 15);
  if (z < 2) {
    unsigned short* O = z ? Kb : Qb;
#pragma unroll
    for (int m = 0; m < 4; ++m)
#pragma unroll
      for (int n = 0; n < 4; ++n)
#pragma unroll
        for (int j = 0; j < 4; ++j) {
          size_t r = rb + (size_t)(m * 16 + j);
          O[r * DD + (size_t)(cb + n * 16)] = f2bf(acc[m][n][j]);
        }
  } else {
#pragma unroll
    for (int m = 0; m < 4; ++m)
#pragma unroll
      for (int n = 0; n < 4; ++n)
#pragma unroll
        for (int j = 0; j < 4; ++j) {
          size_t r = rb + (size_t)(m * 16 + j);
          size_t bb = r >> 11, s = r & 2047;
          Vtb[((bb * DD + (size_t)(cb + n * 16)) << 11) + s] = f2bf(acc[m][n][j]);
        }
  }
}

// ---------------------------------------------------------------------------
// Kernel 3 (fused flash attention PARTIAL, split-KV for 2 blocks/CU):
// 512 blocks: b = idx&7 (XCD-aligned), half = (idx>>3)&1, qt = idx>>4.
// Each block: 64 q-rows, keys [half*1024, half*1024+1024) in 32 iters of 32.
// Same verified structure as r4: phase-split waves (QK/softmax per-wave rows,
// PV per-wave d-slice), K via global_load_lds after bar B, V reg-staged (T14),
// defer-max (T13). Epilogue writes UNNORMALIZED O' (fp32) + per-row (m,l).
//
// LDS swizzles (involutions on 16B slots, r3/r4-verified):
//   K [32][512]: slot' = slot ^ (key & 7)
//   V [512][32]: slot' = slot ^ ((d >> 1) & 3)
//   P [64][32] : slot' = slot ^ ((q >> 1) & 3)
// ---------------------------------------------------------------------------
__device__ __forceinline__ void stage_K(const unsigned short* __restrict__ Kg,
                                        int kt, unsigned short* dst, int t) {
#pragma unroll
  for (int p = 0; p < 8; ++p) {
    int row = 4 * p + (t >> 6);                 // key row 0..31
    int lslot = (t & 63) ^ (row & 7);           // pre-swizzled source slot
    gload_lds16(Kg + (size_t)(kt * 32 + row) * DD + lslot * 8,
                dst + p * 2048 + t * 8);
  }
}

__global__ __launch_bounds__(256, 2) void fused_attn_partial_k(
    const unsigned short* __restrict__ Qb,
    const unsigned short* __restrict__ Kb,
    const unsigned short* __restrict__ Vtb,
    const int* __restrict__ mask,
    float* __restrict__ Op,      // [2][16384][512] unnormalized partials
    float* __restrict__ stats)   // m: [2][16384] @0 ; l: [2][16384] @32768
{
  __shared__ __align__(16) unsigned short Kl[32 * 512];   // 32 KB
  __shared__ __align__(16) unsigned short Vl[512 * 32];   // 32 KB
  __shared__ __align__(16) unsigned short Pl[64 * 32];    // 4 KB
  __shared__ float sclS[64];
  __shared__ int flagS[4];

  const int t = threadIdx.x;
  const int l = t & 63;
  const int w = t >> 6;
  const int b = blockIdx.x & 7;                 // batch -> XCD aligned
  const int half = (blockIdx.x >> 3) & 1;
  const int qt = blockIdx.x >> 4;
  const int kt0 = half * 32;
  const size_t bs0 = (size_t)b * SS + (size_t)qt * 64;   // global q-row base

  const unsigned short* Qg = Qb + (bs0 + (size_t)(w * 16)) * DD;
  const unsigned short* Kg = Kb + (size_t)b * ((size_t)SS * DD);
  const unsigned short* Vg = Vtb + (size_t)b * ((size_t)DD * SS);
  const int* mk = mask + ((size_t)b << 11);

  // Q fragments: wave's 16 q-rows, 16 k-steps of 32
  bf16x8 qf[16];
  {
    const unsigned short* qrow = Qg + (size_t)(l & 15) * DD + (l >> 4) * 8;
#pragma unroll
    for (int ks = 0; ks < 16; ++ks) qf[ks] = *(const bf16x8*)(qrow + ks * 32);
  }

  f32x4 oacc[32];
#pragma unroll
  for (int fn = 0; fn < 32; ++fn) oacc[fn] = (f32x4){0.f, 0.f, 0.f, 0.f};
  float mrow[4] = {-1e30f, -1e30f, -1e30f, -1e30f};
  float lrow[4] = {0.f, 0.f, 0.f, 0.f};

  const float SCALE = 0.022097086912079608f;    // 1/sqrt(2048)

  // V chunk mapping: thread t handles (d = 64p + (t>>2), slot = t&3)
  const int vd = t >> 2;
  const int vs = t & 3;

  // prologue: V[kt0] -> regs, K[kt0] -> LDS
  u32x4 vr[8];
#pragma unroll
  for (int p = 0; p < 8; ++p) {
    int d = 64 * p + vd;
    vr[p] = *(const u32x4*)(Vg + (size_t)d * SS + (size_t)(kt0 * 32) + vs * 8);
  }
  stage_K(Kg, kt0, Kl, t);

  for (int kt = kt0; kt < kt0 + 32; ++kt) {
    __syncthreads();  // bar A: K[kt] staged, V[kt] regs ready, prev PV done

    // ---- V[kt]: regs -> LDS (swizzled write)
#pragma unroll
    for (int p = 0; p < 8; ++p) {
      int d = 64 * p + vd;
      int s2 = vs ^ ((d >> 1) & 3);
      *(u32x4*)(Vl + d * 32 + s2 * 8) = vr[p];
    }

    // ---- QK: wave w -> S[16 q][32 k]
    f32x4 sacc[2];
    sacc[0] = (f32x4){0.f, 0.f, 0.f, 0.f};
    sacc[1] = (f32x4){0.f, 0.f, 0.f, 0.f};
    __builtin_amdgcn_s_setprio(1);
#pragma unroll
    for (int fn = 0; fn < 2; ++fn) {
      const int key = fn * 16 + (l & 15);
      const unsigned short* krow = Kl + key * 512;
      const int kx = key & 7;
#pragma unroll
      for (int ks = 0; ks < 16; ++ks) {
        int slot = ks * 4 + (l >> 4);
        bf16x8 kf = *(const bf16x8*)(krow + ((slot ^ kx) * 8));
        sacc[fn] = __builtin_amdgcn_mfma_f32_16x16x32_bf16(qf[ks], kf, sacc[fn], 0, 0, 0);
      }
    }
    __builtin_amdgcn_s_setprio(0);

    // ---- issue V[kt+1] global loads (latency hides under softmax+PV)
    if (kt + 1 < kt0 + 32) {
#pragma unroll
      for (int p = 0; p < 8; ++p) {
        int d = 64 * p + vd;
        vr[p] = *(const u32x4*)(Vg + (size_t)d * SS + (size_t)((kt + 1) * 32) + vs * 8);
      }
    }

    // ---- masked online softmax with defer-max (rows (l>>4)*4+j of wave w)
    const int mk0 = mk[kt * 32 + (l & 15)];
    const int mk1 = mk[kt * 32 + 16 + (l & 15)];
    float s0[4], s1[4], pmax[4];
    bool need = false;
#pragma unroll
    for (int j = 0; j < 4; ++j) {
      s0[j] = mk0 ? sacc[0][j] * SCALE : -1e30f;
      s1[j] = mk1 ? sacc[1][j] * SCALE : -1e30f;
      float mx = fmaxf(s0[j], s1[j]);
      mx = fmaxf(mx, __shfl_xor(mx, 1));
      mx = fmaxf(mx, __shfl_xor(mx, 2));
      mx = fmaxf(mx, __shfl_xor(mx, 4));
      mx = fmaxf(mx, __shfl_xor(mx, 8));
      pmax[j] = mx;
      need = need || (mx > mrow[j] + 8.f);
    }
    need = (bool)__any((int)need);
    float sclj[4] = {1.f, 1.f, 1.f, 1.f};
    if (need) {
#pragma unroll
      for (int j = 0; j < 4; ++j) {
        float mnew = fmaxf(mrow[j], pmax[j]);
        sclj[j] = __expf(mrow[j] - mnew);
        mrow[j] = mnew;
        lrow[j] *= sclj[j];
      }
    }
    unsigned short p0[4], p1[4];
#pragma unroll
    for (int j = 0; j < 4; ++j) {
      float e0 = mk0 ? __expf(s0[j] - mrow[j]) : 0.f;
      float e1 = mk1 ? __expf(s1[j] - mrow[j]) : 0.f;
      float r = e0 + e1;
      r += __shfl_xor(r, 1);
      r += __shfl_xor(r, 2);
      r += __shfl_xor(r, 4);
      r += __shfl_xor(r, 8);
      lrow[j] += r;
      p0[j] = f2bf(e0);
      p1[j] = f2bf(e1);
    }
    // P -> LDS (rows w*16.., swizzled)
#pragma unroll
    for (int j = 0; j < 4; ++j) {
      int row = w * 16 + (l >> 4) * 4 + j;
      int x = ((row >> 1) & 3) << 3;
      Pl[row * 32 + (((l & 15)) ^ x)]      = p0[j];
      Pl[row * 32 + ((16 + (l & 15)) ^ x)] = p1[j];
    }
    if ((l & 15) == 0) {
#pragma unroll
      for (int j = 0; j < 4; ++j) sclS[w * 16 + (l >> 4) * 4 + j] = sclj[j];
      if (l == 0) flagS[w] = need ? 1 : 0;
    }

    __syncthreads();  // bar B: P/scl/flags visible; K buffer free

    // ---- issue K[kt+1] -> LDS (hides under PV)
    if (kt + 1 < kt0 + 32) stage_K(Kg, kt + 1, Kl, t);

    // ---- PV: wave w -> O[64 q][d-slice w*128..+128)
    int needR = flagS[0] | flagS[1] | flagS[2] | flagS[3];
    if (needR) {
#pragma unroll
      for (int m = 0; m < 4; ++m) {
        f32x4 sv = *(const f32x4*)(sclS + m * 16 + (l >> 4) * 4);
#pragma unroll
        for (int n = 0; n < 8; ++n)
#pragma unroll
          for (int j = 0; j < 4; ++j) oacc[m * 8 + n][j] *= sv[j];
      }
    }
    bf16x8 pa[4];
#pragma unroll
    for (int m = 0; m < 4; ++m) {
      int row = m * 16 + (l & 15);
      int slot = (l >> 4) ^ ((row >> 1) & 3);
      pa[m] = *(const bf16x8*)(Pl + row * 32 + slot * 8);
    }
    __builtin_amdgcn_s_setprio(1);
#pragma unroll
    for (int n = 0; n < 8; ++n) {
      int d = w * 128 + n * 16 + (l & 15);
      int vslot = (l >> 4) ^ ((d >> 1) & 3);
      bf16x8 vf = *(const bf16x8*)(Vl + d * 32 + vslot * 8);
#pragma unroll
      for (int m = 0; m < 4; ++m)
        oacc[m * 8 + n] = __builtin_amdgcn_mfma_f32_16x16x32_bf16(pa[m], vf, oacc[m * 8 + n], 0, 0, 0);
    }
    __builtin_amdgcn_s_setprio(0);
  }

  // ---- epilogue: write unnormalized O' and per-row stats
  if ((l & 15) == 0) {
#pragma unroll
    for (int j = 0; j < 4; ++j) {
      size_t grow = bs0 + (size_t)(w * 16 + (l >> 4) * 4 + j);
      stats[(size_t)half * 16384 + grow] = mrow[j];
      stats[32768 + (size_t)half * 16384 + grow] = lrow[j];
    }
  }
  float* Og = Op + (size_t)half * 8388608 + bs0 * DD;
#pragma unroll
  for (int m = 0; m < 4; ++m) {
#pragma unroll
    for (int n = 0; n < 8; ++n) {
      int d = w * 128 + n * 16 + (l & 15);
#pragma unroll
      for (int j = 0; j < 4; ++j) {
        int q = m * 16 + (l >> 4) * 4 + j;
        Og[(size_t)q * DD + d] = oacc[m * 8 + n][j];
      }
    }
  }
}

// ---------------------------------------------------------------------------
// Kernel 4: combine the two KV-halves.
// out[r][d] = (w0*O'0 + w1*O'1) / (w0*l0 + w1*l1),  w_h = exp(m_h - max(m)).
// ---------------------------------------------------------------------------
__global__ __launch_bounds__(256) void combine_k(
    const float* __restrict__ Op, const float* __restrict__ stats,
    float* __restrict__ Out)
{
  int gid = blockIdx.x * 256 + threadIdx.x;      // 2,097,152 threads total
  int r = gid >> 7;
  int d4 = (gid & 127) << 2;
  float m0 = stats[r],         m1 = stats[16384 + r];
  float l0 = stats[32768 + r], l1 = stats[32768 + 16384 + r];
  float M = fmaxf(m0, m1);
  float w0 = __expf(m0 - M), w1 = __expf(m1 - M);
  float inv = 1.f / (w0 * l0 + w1 * l1);
  f32x4 a = *(const f32x4*)(Op + (size_t)r * DD + d4);
  f32x4 c = *(const f32x4*)(Op + 8388608 + (size_t)r * DD + d4);
  f32x4 o;
#pragma unroll
  for (int j = 0; j < 4; ++j) o[j] = (w0 * a[j] + w1 * c[j]) * inv;
  *(f32x4*)(Out + (size_t)r * DD + d4) = o;
}

// ---------------------------------------------------------------------------
// Workspace layout (ushort elements):
//   Xb   @ 0         : 8388608   (bf16 X; first 131072 ushorts reused as
//                                 fp32 stats[65536] AFTER qkv_gemm_k)
//   Wall @ 8388608   : 786432    (bf16 Wq|Wk|Wv)
//   Qb   @ 9175040   : 8388608
//   Kb   @ 17563648  : 8388608
//   Vtb  @ 25952256  : 8388608   ([b][d][s])
//   Op   @ 34340864  : 33554432 ushorts = fp32[2][16384][512] partials
// ---------------------------------------------------------------------------
extern "C" void kernel_launch(void* const* d_in, const int* in_sizes, int n_in,
                              void* d_out, int out_size, void* d_ws, size_t ws_size,
                              hipStream_t stream) {
  const float* X    = (const float*)d_in[0];
  const int*   mask = (const int*)d_in[1];
  const float* Wq   = (const float*)d_in[2];
  const float* Wk   = (const float*)d_in[3];
  const float* Wv   = (const float*)d_in[4];

  unsigned short* ws   = (unsigned short*)d_ws;
  unsigned short* Xb   = ws;
  unsigned short* Wall = ws + 8388608;
  unsigned short* Qb   = ws + 9175040;
  unsigned short* Kb   = ws + 17563648;
  unsigned short* Vtb  = ws + 25952256;
  float* Op    = (float*)(ws + 34340864);
  float* stats = (float*)ws;                    // overlays Xb (dead after qkv)
  float* Out = (float*)d_out;

  // 1) fp32 -> bf16 conversion
  convert_k<<<8960, 256, 0, stream>>>(X, Wq, Wk, Wv, ws);

  // 2) Q/K/V projections
  qkv_gemm_k<<<dim3(4, 128, 3), 256, 0, stream>>>(Xb, Wall, Qb, Kb, Vtb);

  // 3) fused flash attention partials (split-KV, 2 blocks/CU)
  fused_attn_partial_k<<<512, 256, 0, stream>>>(Qb, Kb, Vtb, mask, Op, stats);

  // 4) combine halves -> fp32 output
  combine_k<<<8192, 256, 0, stream>>>(Op, stats, Out);
}

// Round 6
// 254.706 us; speedup vs baseline: 2.7466x; 2.7466x over previous
//
#include <hip/hip_runtime.h>
#include <cstdint>
#include <cstddef>

// Problem constants
#define BB 8
#define SS 2048
#define DD 512

typedef __attribute__((ext_vector_type(8))) short bf16x8;
typedef __attribute__((ext_vector_type(4))) float f32x4;

__device__ __forceinline__ unsigned short f2bf(float f) {
  unsigned int u = __builtin_bit_cast(unsigned int, f);
  u = (u + 0x7FFFu + ((u >> 16) & 1u)) >> 16;  // RNE
  return (unsigned short)u;
}
__device__ __forceinline__ float bf2f(unsigned short s) {
  return __builtin_bit_cast(float, ((unsigned int)s) << 16);
}

__device__ __forceinline__ void gload_lds16(const unsigned short* g, unsigned short* l) {
  __builtin_amdgcn_global_load_lds(
      (const __attribute__((address_space(1))) void*)g,
      (__attribute__((address_space(3))) void*)l, 16, 0, 0);
}

// ---------------------------------------------------------------------------
// 128x128-tile bf16 GEMM mainloop (m97 structure).
// A[M,K] row-major (K contiguous), B[N,K] row-major (K contiguous) = B^T input.
// 256 threads = 4 waves arranged 2x2; each wave computes a 64x64 sub-tile
// as 4x4 fragments of 16x16. BK=32. LDS double-buffered via global_load_lds.
// ---------------------------------------------------------------------------
__device__ __forceinline__ void gemm_tile(
    const unsigned short* __restrict__ A,
    const unsigned short* __restrict__ B,
    int K, unsigned short* lA, unsigned short* lB,
    f32x4 acc[4][4], size_t m0, size_t n0)
{
  const int t = threadIdx.x;
  const int l = t & 63;
  const int w = t >> 6;
  const int wr = w >> 1, wc = w & 1;
  const size_t K64 = (size_t)K * 64;

  const unsigned short* gA = A + (m0 + (size_t)(t >> 2)) * (size_t)K + (size_t)((t & 3) * 8);
  const unsigned short* gB = B + (n0 + (size_t)(t >> 2)) * (size_t)K + (size_t)((t & 3) * 8);

  const int ar = (wr * 64 + (l & 15)) * 32 + (l >> 4) * 8;
  const int br = (wc * 64 + (l & 15)) * 32 + (l >> 4) * 8;

  const int nk = K >> 5;
  int buf = 0;

  gload_lds16(gA, lA + t * 8);
  gload_lds16(gA + K64, lA + 2048 + t * 8);
  gload_lds16(gB, lB + t * 8);
  gload_lds16(gB + K64, lB + 2048 + t * 8);

  for (int kt = 0; kt < nk; ++kt) {
    __syncthreads();  // stage(kt) complete (compiler drains vmcnt before barrier)
    if (kt + 1 < nk) {
      const int ko = (kt + 1) << 5;
      const int lo = (buf ^ 1) * 4096;
      gload_lds16(gA + ko, lA + lo + t * 8);
      gload_lds16(gA + ko + K64, lA + lo + 2048 + t * 8);
      gload_lds16(gB + ko, lB + lo + t * 8);
      gload_lds16(gB + ko + K64, lB + lo + 2048 + t * 8);
    }
    const unsigned short* pa = lA + buf * 4096 + ar;
    const unsigned short* pb = lB + buf * 4096 + br;
    bf16x8 af[4], bfr[4];
#pragma unroll
    for (int m = 0; m < 4; ++m) af[m] = *(const bf16x8*)(pa + m * 512);
#pragma unroll
    for (int n = 0; n < 4; ++n) bfr[n] = *(const bf16x8*)(pb + n * 512);
#pragma unroll
    for (int m = 0; m < 4; ++m)
#pragma unroll
      for (int n = 0; n < 4; ++n)
        acc[m][n] = __builtin_amdgcn_mfma_f32_16x16x32_bf16(af[m], bfr[n], acc[m][n], 0, 0, 0);
    buf ^= 1;
  }
}

// ---------------------------------------------------------------------------
// Kernel 1: convert X (8.39M f32) and Wq|Wk|Wv (3 x 262144 f32) to bf16 in ws.
// ---------------------------------------------------------------------------
__global__ __launch_bounds__(256) void convert_k(
    const float* __restrict__ X, const float* __restrict__ Wq,
    const float* __restrict__ Wk, const float* __restrict__ Wv,
    unsigned short* __restrict__ dst)
{
  const size_t NXe = (size_t)BB * SS * DD;  // 8388608
  const size_t NWe = (size_t)DD * DD;       // 262144
  size_t i = ((size_t)blockIdx.x * 256 + threadIdx.x) * 4;
  const float* src;
  size_t off;
  if (i < NXe)                { src = X;  off = i; }
  else if (i < NXe + NWe)     { src = Wq; off = i - NXe; }
  else if (i < NXe + 2 * NWe) { src = Wk; off = i - NXe - NWe; }
  else                        { src = Wv; off = i - NXe - 2 * NWe; }
  float4 f = *(const float4*)(src + off);
  ushort4 o;
  o.x = f2bf(f.x); o.y = f2bf(f.y); o.z = f2bf(f.z); o.w = f2bf(f.w);
  *(ushort4*)(dst + i) = o;
}

// ---------------------------------------------------------------------------
// Kernel 2: QKV projections. z=0 -> Q [16384,512] PRE-SCALED by 1/sqrt(S),
// z=1 -> K [16384,512], z=2 -> V transposed per batch: Vt[b][d][s].
// ---------------------------------------------------------------------------
__global__ __launch_bounds__(256, 2) void qkv_gemm_k(
    const unsigned short* __restrict__ Xb,
    const unsigned short* __restrict__ Wall,
    unsigned short* __restrict__ Qb,
    unsigned short* __restrict__ Kb,
    unsigned short* __restrict__ Vtb)
{
  __shared__ __align__(16) unsigned short lA[8192];
  __shared__ __align__(16) unsigned short lB[8192];
  const int z = blockIdx.z;
  const unsigned short* Bw = Wall + (size_t)z * (DD * DD);
  const size_t m0 = (size_t)blockIdx.y * 128;
  const size_t n0 = (size_t)blockIdx.x * 128;
  f32x4 acc[4][4];
#pragma unroll
  for (int m = 0; m < 4; ++m)
#pragma unroll
    for (int n = 0; n < 4; ++n) acc[m][n] = (f32x4){0.f, 0.f, 0.f, 0.f};

  gemm_tile(Xb, Bw, DD, lA, lB, acc, m0, n0);

  const int t = threadIdx.x, l = t & 63, w = t >> 6, wr = w >> 1, wc = w & 1;
  const size_t rb = m0 + (size_t)(wr * 64 + ((l >> 4) * 4));
  const int cb = (int)n0 + wc * 64 + (l & 15);
  if (z < 2) {
    unsigned short* O = z ? Kb : Qb;
    const float sc = z ? 1.0f : 0.022097086912079608f;  // fold 1/sqrt(S) into Q
#pragma unroll
    for (int m = 0; m < 4; ++m)
#pragma unroll
      for (int n = 0; n < 4; ++n)
#pragma unroll
        for (int j = 0; j < 4; ++j) {
          size_t r = rb + (size_t)(m * 16 + j);
          O[r * DD + (size_t)(cb + n * 16)] = f2bf(acc[m][n][j] * sc);
        }
  } else {
#pragma unroll
    for (int m = 0; m < 4; ++m)
#pragma unroll
      for (int n = 0; n < 4; ++n)
#pragma unroll
        for (int j = 0; j < 4; ++j) {
          size_t r = rb + (size_t)(m * 16 + j);
          size_t bb = r >> 11, s = r & 2047;
          Vtb[((bb * DD + (size_t)(cb + n * 16)) << 11) + s] = f2bf(acc[m][n][j]);
        }
  }
}

// ---------------------------------------------------------------------------
// Kernel 3: scores = Qs_b . K_b^T (already scaled) -> bf16 [b][2048][2048]
// Grid: 1D 2048. Swizzle: b = lin&7 (batch <-> XCD, K+Q L2-resident);
// within batch y-inner (K-panel hot for 16 consecutive blocks, the 16
// Q-panels = 2 MB cycle resident in the XCD's 4 MB L2).
// ---------------------------------------------------------------------------
__global__ __launch_bounds__(256, 2) void scores_gemm_k(
    const unsigned short* __restrict__ Qb,
    const unsigned short* __restrict__ Kb,
    unsigned short* __restrict__ Sc)
{
  __shared__ __align__(16) unsigned short lA[8192];
  __shared__ __align__(16) unsigned short lB[8192];
  const int lin = blockIdx.x;
  const int b = lin & 7;
  const int pos = lin >> 3;          // 0..255
  const int ty = pos & 15;           // q-row tile (inner)
  const int tx = pos >> 4;           // key tile (outer)
  const unsigned short* A  = Qb + (size_t)b * (SS * DD);
  const unsigned short* Bp = Kb + (size_t)b * (SS * DD);
  unsigned short* C = Sc + (size_t)b * ((size_t)SS * SS);
  const size_t m0 = (size_t)ty * 128;
  const size_t n0 = (size_t)tx * 128;
  f32x4 acc[4][4];
#pragma unroll
  for (int m = 0; m < 4; ++m)
#pragma unroll
    for (int n = 0; n < 4; ++n) acc[m][n] = (f32x4){0.f, 0.f, 0.f, 0.f};

  gemm_tile(A, Bp, DD, lA, lB, acc, m0, n0);

  const int t = threadIdx.x, l = t & 63, w = t >> 6, wr = w >> 1, wc = w & 1;
  const size_t rb = m0 + (size_t)(wr * 64 + ((l >> 4) * 4));
  const int cb = (int)n0 + wc * 64 + (l & 15);
#pragma unroll
  for (int m = 0; m < 4; ++m)
#pragma unroll
    for (int n = 0; n < 4; ++n)
#pragma unroll
      for (int j = 0; j < 4; ++j) {
        size_t r = rb + (size_t)(m * 16 + j);
        C[r * SS + (size_t)(cb + n * 16)] = f2bf(acc[m][n][j]);
      }
}

// ---------------------------------------------------------------------------
// Kernel 4: in-place masked softmax over each score row (scores pre-scaled).
// One block (256 threads, 4 waves) per row; 8 elements/thread.
// ---------------------------------------------------------------------------
__global__ __launch_bounds__(256) void softmax_k(
    unsigned short* __restrict__ Sc, const int* __restrict__ mask)
{
  __shared__ float smax[4], ssum[4];
  const int row = blockIdx.x;          // 0..16383
  const int b = row >> 11;
  unsigned short* p = Sc + (size_t)row * SS;
  const int* mk = mask + ((size_t)b << 11);
  const int t = threadIdx.x;
  const int c0 = t * 8;

  bf16x8 sv = *(const bf16x8*)(p + c0);
  int4 ma = *(const int4*)(mk + c0);
  int4 mb = *(const int4*)(mk + c0 + 4);
  int mm[8] = {ma.x, ma.y, ma.z, ma.w, mb.x, mb.y, mb.z, mb.w};
  float v[8];
#pragma unroll
  for (int j = 0; j < 8; ++j) v[j] = bf2f((unsigned short)sv[j]);

  float mx = -3.0e38f;
#pragma unroll
  for (int j = 0; j < 8; ++j) if (mm[j]) mx = fmaxf(mx, v[j]);
#pragma unroll
  for (int off = 32; off >= 1; off >>= 1) mx = fmaxf(mx, __shfl_xor(mx, off));
  const int wid = t >> 6, ln = t & 63;
  if (ln == 0) smax[wid] = mx;
  __syncthreads();
  mx = fmaxf(fmaxf(smax[0], smax[1]), fmaxf(smax[2], smax[3]));

  float e[8];
  float sum = 0.f;
#pragma unroll
  for (int j = 0; j < 8; ++j) { e[j] = mm[j] ? __expf(v[j] - mx) : 0.f; sum += e[j]; }
#pragma unroll
  for (int off = 32; off >= 1; off >>= 1) sum += __shfl_xor(sum, off);
  if (ln == 0) ssum[wid] = sum;
  __syncthreads();
  sum = ssum[0] + ssum[1] + ssum[2] + ssum[3];
  const float inv = 1.f / sum;

  bf16x8 ov;
#pragma unroll
  for (int j = 0; j < 8; ++j) ov[j] = (short)f2bf(e[j] * inv);
  *(bf16x8*)(p + c0) = ov;
}

// ---------------------------------------------------------------------------
// Kernel 5: Out_b = P_b . V_b (A = probs [2048,2048] bf16 k-contig,
// B = Vt [512,2048] bf16 k-contig), fp32 output straight to d_out.
// Grid: 1D 512. Swizzle: b = lin&7 (batch <-> XCD, V=2MB L2-resident);
// within batch x-inner (P-row-panel 512 KB hot for the 4 d-tiles).
// ---------------------------------------------------------------------------
__global__ __launch_bounds__(256, 2) void pv_gemm_k(
    const unsigned short* __restrict__ Sc,
    const unsigned short* __restrict__ Vtb,
    float* __restrict__ Out)
{
  __shared__ __align__(16) unsigned short lA[8192];
  __shared__ __align__(16) unsigned short lB[8192];
  const int lin = blockIdx.x;
  const int b = lin & 7;
  const int pos = lin >> 3;          // 0..63
  const int tx = pos & 3;            // d tile (inner)
  const int ty = pos >> 2;           // q-row tile (outer)
  const unsigned short* A  = Sc + (size_t)b * ((size_t)SS * SS);
  const unsigned short* Bp = Vtb + (size_t)b * (DD * SS);
  float* C = Out + (size_t)b * (SS * DD);
  const size_t m0 = (size_t)ty * 128;
  const size_t n0 = (size_t)tx * 128;
  f32x4 acc[4][4];
#pragma unroll
  for (int m = 0; m < 4; ++m)
#pragma unroll
    for (int n = 0; n < 4; ++n) acc[m][n] = (f32x4){0.f, 0.f, 0.f, 0.f};

  gemm_tile(A, Bp, SS, lA, lB, acc, m0, n0);

  const int t = threadIdx.x, l = t & 63, w = t >> 6, wr = w >> 1, wc = w & 1;
  const size_t rb = m0 + (size_t)(wr * 64 + ((l >> 4) * 4));
  const int cb = (int)n0 + wc * 64 + (l & 15);
#pragma unroll
  for (int m = 0; m < 4; ++m)
#pragma unroll
    for (int n = 0; n < 4; ++n)
#pragma unroll
      for (int j = 0; j < 4; ++j) {
        size_t r = rb + (size_t)(m * 16 + j);
        C[r * DD + (size_t)(cb + n * 16)] = acc[m][n][j];
      }
}

// ---------------------------------------------------------------------------
// Workspace layout (ushort elements):
//   Xb   @ 0         : 8388608   (bf16 X)
//   Wall @ 8388608   : 786432    (bf16 Wq|Wk|Wv)
//   Qb   @ 9175040   : 8388608   (pre-scaled by 1/sqrt(S))
//   Kb   @ 17563648  : 8388608
//   Vtb  @ 25952256  : 8388608   ([b][d][s])
//   Sc   @ 34340864  : 33554432  (scores -> probs, in place)
// ---------------------------------------------------------------------------
extern "C" void kernel_launch(void* const* d_in, const int* in_sizes, int n_in,
                              void* d_out, int out_size, void* d_ws, size_t ws_size,
                              hipStream_t stream) {
  const float* X    = (const float*)d_in[0];
  const int*   mask = (const int*)d_in[1];
  const float* Wq   = (const float*)d_in[2];
  const float* Wk   = (const float*)d_in[3];
  const float* Wv   = (const float*)d_in[4];

  unsigned short* ws   = (unsigned short*)d_ws;
  unsigned short* Xb   = ws;
  unsigned short* Wall = ws + 8388608;
  unsigned short* Qb   = ws + 9175040;
  unsigned short* Kb   = ws + 17563648;
  unsigned short* Vtb  = ws + 25952256;
  unsigned short* Sc   = ws + 34340864;
  float* Out = (float*)d_out;

  // 1) fp32 -> bf16 conversion of X and the three weight matrices
  convert_k<<<8960, 256, 0, stream>>>(X, Wq, Wk, Wv, ws);

  // 2) Q/K/V projections (z = 0/1/2); Q pre-scaled
  qkv_gemm_k<<<dim3(4, 128, 3), 256, 0, stream>>>(Xb, Wall, Qb, Kb, Vtb);

  // 3) scaled scores per batch (XCD-blocked)
  scores_gemm_k<<<2048, 256, 0, stream>>>(Qb, Kb, Sc);

  // 4) masked softmax in place
  softmax_k<<<16384, 256, 0, stream>>>(Sc, mask);

  // 5) probs . V -> fp32 output (XCD-blocked)
  pv_gemm_k<<<512, 256, 0, stream>>>(Sc, Vtb, Out);
}